// Round 10
// baseline (438.174 us; speedup 1.0000x reference)
//
#include <hip/hip_runtime.h>

// Problem constants (from reference)
#define NL0 300000
#define NL1 60000
#define NL2 15000
#define NL3 4000
#define NE0 960000
#define NE1 240000
#define NE2 64000
#define E_ALL (NE0 + NE1 + NE2)
#define F_IN 256
#define F_HID 128
#define F_OUT 47

// Concatenated CSR row layout:
//   [0, 60000)        : layer0 dst
//   [60000, 75000)    : layer1 dst
//   [75000, 79000)    : layer2 dst
#define RBASE1 NL1
#define RBASE2 (NL1 + NL2)
#define NROWS (NL1 + NL2 + NL3)

typedef __attribute__((ext_vector_type(8))) short short8v;   // 8 bf16 (4 VGPR)
typedef __attribute__((ext_vector_type(4))) float f32x4;

// ---------------------------------------------------------------------------
// Wave-wide (64-lane) inclusive scan
// ---------------------------------------------------------------------------
__device__ inline int wave_incl_scan(int v) {
    int lane = threadIdx.x & 63;
#pragma unroll
    for (int off = 1; off < 64; off <<= 1) {
        int t = __shfl_up(v, off, 64);
        if (lane >= off) v += t;
    }
    return v;
}

// fp32 -> (bf16 hi, bf16 lo) split (truncation; lo captures hi's error)
__device__ inline void bf16_split(float x, unsigned short& hi, unsigned short& lo) {
    unsigned int u = __float_as_uint(x);
    hi = (unsigned short)(u >> 16);
    float fh = __uint_as_float(u & 0xffff0000u);
    float l = x - fh;
    lo = (unsigned short)(__float_as_uint(l) >> 16);
}

// ---------------------------------------------------------------------------
// Fused histogram over all three layers' edges
// ---------------------------------------------------------------------------
__global__ void histogram_all(const int* __restrict__ dst0, const int* __restrict__ dst1,
                              const int* __restrict__ dst2, int* __restrict__ cnt) {
    int i = blockIdx.x * blockDim.x + threadIdx.x;
    if (i >= E_ALL) return;
    int k;
    if (i < NE0) {
        k = dst0[i];
    } else if (i < NE0 + NE1) {
        k = RBASE1 + dst1[i - NE0];
    } else {
        k = RBASE2 + dst2[i - NE0 - NE1];
    }
    atomicAdd(&cnt[k], 1);
}

// ---------------------------------------------------------------------------
// Exclusive scan over NROWS counters (chunked: per-1024 scan + totals + add)
// ---------------------------------------------------------------------------
__global__ __launch_bounds__(1024) void scan_block(const int* __restrict__ cnt, int N,
                                                   int* __restrict__ row_start,
                                                   int* __restrict__ blocksum) {
    __shared__ int wsum[16];
    int i = blockIdx.x * 1024 + threadIdx.x;
    int lane = threadIdx.x & 63, wid = threadIdx.x >> 6;
    int v = (i < N) ? cnt[i] : 0;
    int incl = wave_incl_scan(v);
    if (lane == 63) wsum[wid] = incl;
    __syncthreads();
    if (threadIdx.x < 16) {
        int w = wsum[threadIdx.x];
#pragma unroll
        for (int off = 1; off < 16; off <<= 1) {
            int t = __shfl_up(w, off, 64);
            if ((int)threadIdx.x >= off) w += t;
        }
        wsum[threadIdx.x] = w;
    }
    __syncthreads();
    int woff = wid ? wsum[wid - 1] : 0;
    if (i < N) row_start[i] = woff + incl - v;
    if (threadIdx.x == 0) blocksum[blockIdx.x] = wsum[15];
}

__global__ __launch_bounds__(1024) void scan_totals(int* __restrict__ bs, int nb) {
    __shared__ int wsum[16];
    int i = threadIdx.x;
    int lane = i & 63, wid = i >> 6;
    int v = (i < nb) ? bs[i] : 0;
    int incl = wave_incl_scan(v);
    if (lane == 63) wsum[wid] = incl;
    __syncthreads();
    if (i < 16) {
        int w = wsum[i];
#pragma unroll
        for (int off = 1; off < 16; off <<= 1) {
            int t = __shfl_up(w, off, 64);
            if (i >= off) w += t;
        }
        wsum[i] = w;
    }
    __syncthreads();
    int woff = wid ? wsum[wid - 1] : 0;
    if (i < nb) bs[i] = woff + incl - v;
}

__global__ __launch_bounds__(1024) void add_offsets(int* __restrict__ row_start,
                                                    const int* __restrict__ bs, int N, int E,
                                                    int* __restrict__ cursor) {
    int i = blockIdx.x * 1024 + threadIdx.x;
    if (i < N) {
        int s = row_start[i] + bs[blockIdx.x];
        row_start[i] = s;
        cursor[i] = s;
    }
    if (i == 0) row_start[N] = E;
}

// ---------------------------------------------------------------------------
// Fused fill: scatter edge src ids into dst-grouped order (all layers)
// ---------------------------------------------------------------------------
__global__ void fill_all(const int* __restrict__ src0, const int* __restrict__ dst0,
                         const int* __restrict__ src1, const int* __restrict__ dst1,
                         const int* __restrict__ src2, const int* __restrict__ dst2,
                         int* __restrict__ cursor, int* __restrict__ ss) {
    int i = blockIdx.x * blockDim.x + threadIdx.x;
    if (i >= E_ALL) return;
    int k, s;
    if (i < NE0) {
        s = src0[i];
        k = dst0[i];
    } else if (i < NE0 + NE1) {
        int e = i - NE0;
        s = src1[e];
        k = RBASE1 + dst1[e];
    } else {
        int e = i - NE0 - NE1;
        s = src2[e];
        k = RBASE2 + dst2[e];
    }
    int p = atomicAdd(&cursor[k], 1);
    ss[p] = s;
}

// ---------------------------------------------------------------------------
// W1 prep: split + transpose W[256][128] fp32 -> wt_hi/wt_lo [128][256] bf16
// ---------------------------------------------------------------------------
__global__ void wprep(const float* __restrict__ W,
                      unsigned short* __restrict__ Whi, unsigned short* __restrict__ Wlo) {
    int idx = blockIdx.x * 256 + threadIdx.x;          // 32768 = 256*128
    int k = idx >> 7, c = idx & 127;                   // W[k][c]
    unsigned short h, l;
    bf16_split(W[idx], h, l);
    Whi[c * 256 + k] = h;
    Wlo[c * 256 + k] = l;
}

// ---------------------------------------------------------------------------
// Transform-first layer 0 GEMM: Y[300k,128] = X[300k,256] @ W1  (fp32 out,
// no bias/relu -- those commute past the mean and are applied in gatherY).
// Markidis split (hi*hi + hi*lo + lo*hi) on MFMA 16x16x32.
// Block = 1024 thr (16 waves), W staged pre-split from global to LDS (128 KB,
// XOR-swizzled).  Each wave computes a 16x128 strip; grid = ceil(N/256).
// A-frag: lane(r+16kg) holds X[row=base+r][ks*32+kg*8+j] (converted on load)
// C/D: col = lane&15, row = (lane>>4)*4 + reg   [HW-verified mapping]
// ---------------------------------------------------------------------------
__global__ __launch_bounds__(1024) void xform0(const float* __restrict__ X,
                                               const unsigned short* __restrict__ Whi,
                                               const unsigned short* __restrict__ Wlo,
                                               float* __restrict__ Y, int N) {
    __shared__ unsigned short whi[F_IN * F_HID];   // 64 KB, Wt[c][k] swizzled
    __shared__ unsigned short wlo[F_IN * F_HID];   // 64 KB

    // stage pre-split W (vector copies, swizzled destination)
    for (int ci = threadIdx.x; ci < (F_IN * F_HID) / 8; ci += 1024) {
        int e = ci * 8;                 // element index: c = e>>8, aligned-8 chunk
        int c = e >> 8;
        int swz = e ^ ((c & 7) << 3);
        *(short8v*)(whi + swz) = *(const short8v*)(Whi + e);
        *(short8v*)(wlo + swz) = *(const short8v*)(Wlo + e);
    }
    __syncthreads();

    int lane = threadIdx.x & 63;
    int wid = threadIdx.x >> 6;            // 0..15
    int rowbase = blockIdx.x * 256 + wid * 16;
    int r = lane & 15;
    int kg = lane >> 4;

    size_t arow = (size_t)min(rowbase + r, N - 1);
    const float* pa = X + arow * F_IN + kg * 8;

    f32x4 acc[8];
#pragma unroll
    for (int ct = 0; ct < 8; ++ct) acc[ct] = (f32x4){0.f, 0.f, 0.f, 0.f};

#pragma unroll
    for (int ks = 0; ks < 8; ++ks) {
        float4 x0 = *(const float4*)(pa + ks * 32);
        float4 x1 = *(const float4*)(pa + ks * 32 + 4);
        short8v ahi, alo;
        {
            unsigned short h, l;
            bf16_split(x0.x, h, l); ahi[0] = (short)h; alo[0] = (short)l;
            bf16_split(x0.y, h, l); ahi[1] = (short)h; alo[1] = (short)l;
            bf16_split(x0.z, h, l); ahi[2] = (short)h; alo[2] = (short)l;
            bf16_split(x0.w, h, l); ahi[3] = (short)h; alo[3] = (short)l;
            bf16_split(x1.x, h, l); ahi[4] = (short)h; alo[4] = (short)l;
            bf16_split(x1.y, h, l); ahi[5] = (short)h; alo[5] = (short)l;
            bf16_split(x1.z, h, l); ahi[6] = (short)h; alo[6] = (short)l;
            bf16_split(x1.w, h, l); ahi[7] = (short)h; alo[7] = (short)l;
        }
#pragma unroll
        for (int ct = 0; ct < 8; ++ct) {
            int e = (((ct * 16 + r) << 8) + ks * 32 + kg * 8) ^ ((r & 7) << 3);
            short8v bh = *(const short8v*)(whi + e);
            short8v bl = *(const short8v*)(wlo + e);
            acc[ct] = __builtin_amdgcn_mfma_f32_16x16x32_bf16(ahi, bh, acc[ct], 0, 0, 0);
            acc[ct] = __builtin_amdgcn_mfma_f32_16x16x32_bf16(ahi, bl, acc[ct], 0, 0, 0);
            acc[ct] = __builtin_amdgcn_mfma_f32_16x16x32_bf16(alo, bh, acc[ct], 0, 0, 0);
        }
    }

    int crow = rowbase + kg * 4;
#pragma unroll
    for (int ct = 0; ct < 8; ++ct) {
#pragma unroll
        for (int i = 0; i < 4; ++i) {
            int rr = crow + i;
            if (rr < N) Y[(size_t)rr * F_HID + ct * 16 + r] = acc[ct][i];
        }
    }
}

// ---------------------------------------------------------------------------
// Layer-0 gather over Y (F=128 fp32): one wave per dst row; mean + bias +
// relu fused (h1 = relu(mean(Y[src]) + b1)).  High-occupancy (no LDS).
// ---------------------------------------------------------------------------
__global__ __launch_bounds__(256) void gatherY(const float* __restrict__ Y,
                                               const int* __restrict__ rs,
                                               const int* __restrict__ ss,
                                               const float* __restrict__ b1,
                                               float* __restrict__ h1) {
    int lane = threadIdx.x & 63;
    int r = blockIdx.x * 4 + (threadIdx.x >> 6);
    if (r >= NL1) return;
    int s0 = rs[r], s1 = rs[r + 1];
    int tot = s1 - s0;

    const float* yp = Y + (size_t)lane * 2;
    float2 acc0 = make_float2(0.f, 0.f);
    float2 acc1 = make_float2(0.f, 0.f);
    int e = s0;
    for (; e + 7 < s1; e += 8) {
        int i0 = ss[e], i1 = ss[e + 1], i2 = ss[e + 2], i3 = ss[e + 3];
        int i4 = ss[e + 4], i5 = ss[e + 5], i6 = ss[e + 6], i7 = ss[e + 7];
        float2 v0 = *(const float2*)(yp + (size_t)i0 * F_HID);
        float2 v1 = *(const float2*)(yp + (size_t)i1 * F_HID);
        float2 v2 = *(const float2*)(yp + (size_t)i2 * F_HID);
        float2 v3 = *(const float2*)(yp + (size_t)i3 * F_HID);
        float2 v4 = *(const float2*)(yp + (size_t)i4 * F_HID);
        float2 v5 = *(const float2*)(yp + (size_t)i5 * F_HID);
        float2 v6 = *(const float2*)(yp + (size_t)i6 * F_HID);
        float2 v7 = *(const float2*)(yp + (size_t)i7 * F_HID);
        acc0.x += (v0.x + v1.x) + (v2.x + v3.x);
        acc0.y += (v0.y + v1.y) + (v2.y + v3.y);
        acc1.x += (v4.x + v5.x) + (v6.x + v7.x);
        acc1.y += (v4.y + v5.y) + (v6.y + v7.y);
    }
    for (; e < s1; ++e) {
        int i0 = ss[e];
        float2 v0 = *(const float2*)(yp + (size_t)i0 * F_HID);
        acc0.x += v0.x; acc0.y += v0.y;
    }
    float inv = (tot > 0) ? 1.0f / (float)tot : 0.0f;
    float2 bb = *(const float2*)(b1 + lane * 2);
    float2 o = make_float2(fmaxf((acc0.x + acc1.x) * inv + bb.x, 0.f),
                           fmaxf((acc0.y + acc1.y) * inv + bb.y, 0.f));
    *(float2*)(h1 + (size_t)r * F_HID + lane * 2) = o;
}

// ---------------------------------------------------------------------------
// Fused gather + mean + linear for F_HID-wide layers (layers 1 and 2).
// ---------------------------------------------------------------------------
template <int FOUT, int ROWS, bool RELU>
__global__ __launch_bounds__(256) void gather_linear(const float* __restrict__ h,
                                                     const int* __restrict__ rs,
                                                     const int* __restrict__ ss,
                                                     const float* __restrict__ W,
                                                     const float* __restrict__ bias,
                                                     float* __restrict__ out,
                                                     int N, int rowbase) {
    __shared__ float wtile[128 * FOUT];
    __shared__ float mr[ROWS][128];

    if constexpr (FOUT % 4 == 0) {
        for (int idx = threadIdx.x * 4; idx < 128 * FOUT; idx += 1024)
            *(float4*)&wtile[idx] = *(const float4*)&W[idx];
    } else {
        for (int idx = threadIdx.x; idx < 128 * FOUT; idx += 256)
            wtile[idx] = W[idx];
    }

    int lane = threadIdx.x & 63;
    int w = threadIdx.x >> 6;
    int rb = blockIdx.x * ROWS;
    constexpr int RPW = ROWS / 4;
#pragma unroll
    for (int q = 0; q < RPW; ++q) {
        int lr = w * RPW + q;
        int r = rb + lr;
        float2 acc = make_float2(0.f, 0.f);
        if (r < N) {
            int s0 = rs[rowbase + r], s1 = rs[rowbase + r + 1];
            const float* hp = h + (size_t)lane * 2;
            int e = s0;
            for (; e + 3 < s1; e += 4) {
                int i0 = ss[e], i1 = ss[e + 1], i2 = ss[e + 2], i3 = ss[e + 3];
                float2 v0 = *(const float2*)(hp + (size_t)i0 * F_HID);
                float2 v1 = *(const float2*)(hp + (size_t)i1 * F_HID);
                float2 v2 = *(const float2*)(hp + (size_t)i2 * F_HID);
                float2 v3 = *(const float2*)(hp + (size_t)i3 * F_HID);
                acc.x += (v0.x + v1.x) + (v2.x + v3.x);
                acc.y += (v0.y + v1.y) + (v2.y + v3.y);
            }
            for (; e < s1; ++e) {
                int i0 = ss[e];
                float2 v0 = *(const float2*)(hp + (size_t)i0 * F_HID);
                acc.x += v0.x; acc.y += v0.y;
            }
            float inv = (s1 > s0) ? 1.0f / (float)(s1 - s0) : 0.0f;
            acc.x *= inv; acc.y *= inv;
        }
        *(float2*)&mr[lr][lane * 2] = acc;
    }
    __syncthreads();

    if constexpr (FOUT == 128) {
        int c4 = (threadIdx.x & 31) * 4;
        int r0 = (threadIdx.x >> 5) & 7;
        float4 bb = *(const float4*)&bias[c4];
        float4 a0 = bb, a1 = bb;
#pragma unroll 8
        for (int k = 0; k < 128; ++k) {
            float4 wv = *(const float4*)&wtile[k * 128 + c4];
            float m0 = mr[r0][k];
            float m1 = mr[r0 + 8][k];
            a0.x += m0 * wv.x; a0.y += m0 * wv.y; a0.z += m0 * wv.z; a0.w += m0 * wv.w;
            a1.x += m1 * wv.x; a1.y += m1 * wv.y; a1.z += m1 * wv.z; a1.w += m1 * wv.w;
        }
        if (RELU) {
            a0.x = fmaxf(a0.x, 0.f); a0.y = fmaxf(a0.y, 0.f);
            a0.z = fmaxf(a0.z, 0.f); a0.w = fmaxf(a0.w, 0.f);
            a1.x = fmaxf(a1.x, 0.f); a1.y = fmaxf(a1.y, 0.f);
            a1.z = fmaxf(a1.z, 0.f); a1.w = fmaxf(a1.w, 0.f);
        }
        int ra = rb + r0, rb2 = rb + r0 + 8;
        if (ra < N) *(float4*)&out[(size_t)ra * 128 + c4] = a0;
        if (rb2 < N) *(float4*)&out[(size_t)rb2 * 128 + c4] = a1;
    } else {
        int j = threadIdx.x & 63;
        int rg = threadIdx.x >> 6;
        if (j < FOUT) {
            float bb = bias[j];
            float a0 = bb, a1 = bb;
#pragma unroll 8
            for (int k = 0; k < 128; ++k) {
                float wv = wtile[k * FOUT + j];
                a0 += mr[rg][k] * wv;
                a1 += mr[rg + 4][k] * wv;
            }
            if (RELU) { a0 = fmaxf(a0, 0.f); a1 = fmaxf(a1, 0.f); }
            int ra = rb + rg, rb2 = rb + rg + 4;
            if (ra < N) out[(size_t)ra * FOUT + j] = a0;
            if (rb2 < N) out[(size_t)rb2 * FOUT + j] = a1;
        }
    }
}

// ---------------------------------------------------------------------------

static inline size_t align256(size_t x) { return (x + 255) & ~size_t(255); }

extern "C" void kernel_launch(void* const* d_in, const int* in_sizes, int n_in,
                              void* d_out, int out_size, void* d_ws, size_t ws_size,
                              hipStream_t stream) {
    const float* features = (const float*)d_in[0];
    const int*   src0     = (const int*)d_in[1];
    const int*   dst0     = (const int*)d_in[2];
    const int*   src1     = (const int*)d_in[3];
    const int*   dst1     = (const int*)d_in[4];
    const int*   src2     = (const int*)d_in[5];
    const int*   dst2     = (const int*)d_in[6];
    const float* W1       = (const float*)d_in[7];
    const float* b1       = (const float*)d_in[8];
    const float* W2       = (const float*)d_in[9];
    const float* b2       = (const float*)d_in[10];
    const float* W3       = (const float*)d_in[11];
    const float* b3       = (const float*)d_in[12];
    float* out = (float*)d_out;

    char* p = (char*)d_ws;
    size_t off = 0;
    auto alloc = [&](size_t bytes) {
        char* r = p + off;
        off += align256(bytes);
        return r;
    };
    float* Y  = (float*)alloc(sizeof(float) * (size_t)NL0 * F_HID);   // 154 MB
    float* h1 = (float*)alloc(sizeof(float) * (size_t)NL1 * F_HID);
    float* h2 = (float*)alloc(sizeof(float) * (size_t)NL2 * F_HID);
    unsigned short* wt_hi = (unsigned short*)alloc(sizeof(unsigned short) * F_IN * F_HID);
    unsigned short* wt_lo = (unsigned short*)alloc(sizeof(unsigned short) * F_IN * F_HID);
    int* cnt = (int*)alloc(sizeof(int) * NROWS);
    int* rs  = (int*)alloc(sizeof(int) * (NROWS + 1));
    int* cur = (int*)alloc(sizeof(int) * NROWS);
    int* bs  = (int*)alloc(sizeof(int) * 1024);
    int* ss  = (int*)alloc(sizeof(int) * E_ALL);
    (void)ws_size;

    // ---- Fused CSR build over all layers (hierarchical scan, all tiny) ----
    hipMemsetAsync(cnt, 0, sizeof(int) * NROWS, stream);
    histogram_all<<<(E_ALL + 255) / 256, 256, 0, stream>>>(dst0, dst1, dst2, cnt);
    int nb = (NROWS + 1023) / 1024;
    scan_block<<<nb, 1024, 0, stream>>>(cnt, NROWS, rs, bs);
    scan_totals<<<1, 1024, 0, stream>>>(bs, nb);
    add_offsets<<<nb, 1024, 0, stream>>>(rs, bs, NROWS, E_ALL, cur);
    fill_all<<<(E_ALL + 255) / 256, 256, 0, stream>>>(src0, dst0, src1, dst1, src2, dst2,
                                                      cur, ss);

    // ---- Layer 0 -> 1: transform-first (Y = X@W1), then gather+mean+bias+relu
    wprep<<<(F_IN * F_HID) / 256, 256, 0, stream>>>(W1, wt_hi, wt_lo);
    xform0<<<(NL0 + 255) / 256, 1024, 0, stream>>>(features, wt_hi, wt_lo, Y, NL0);
    gatherY<<<NL1 / 4, 256, 0, stream>>>(Y, rs, ss, b1, h1);

    // ---- Layer 1 -> 2 (fused gather+mean+linear) ----
    gather_linear<128, 16, true><<<(NL2 + 15) / 16, 256, 0, stream>>>(
        h1, rs, ss, W2, b2, h2, NL2, RBASE1);

    // ---- Layer 2 -> 3 (fused gather+mean+linear, no relu) ----
    gather_linear<F_OUT, 8, false><<<(NL3 + 7) / 8, 256, 0, stream>>>(
        h2, rs, ss, W3, b3, out, NL3, RBASE2);
}

// Round 11
// 407.948 us; speedup vs baseline: 1.0741x; 1.0741x over previous
//
#include <hip/hip_runtime.h>

// Problem constants (from reference)
#define NL0 300000
#define NL1 60000
#define NL2 15000
#define NL3 4000
#define NE0 960000
#define NE1 240000
#define NE2 64000
#define E_ALL (NE0 + NE1 + NE2)
#define F_IN 256
#define F_HID 128
#define F_OUT 47

// Concatenated CSR row layout:
//   [0, 60000)        : layer0 dst
//   [60000, 75000)    : layer1 dst
//   [75000, 79000)    : layer2 dst
#define RBASE1 NL1
#define RBASE2 (NL1 + NL2)
#define NROWS (NL1 + NL2 + NL3)

typedef __attribute__((ext_vector_type(8))) short short8v;   // 8 bf16 (4 VGPR)
typedef __attribute__((ext_vector_type(4))) float f32x4;

// ---------------------------------------------------------------------------
// Wave-wide (64-lane) inclusive scan
// ---------------------------------------------------------------------------
__device__ inline int wave_incl_scan(int v) {
    int lane = threadIdx.x & 63;
#pragma unroll
    for (int off = 1; off < 64; off <<= 1) {
        int t = __shfl_up(v, off, 64);
        if (lane >= off) v += t;
    }
    return v;
}

// fp32 -> (bf16 hi, bf16 lo) split (truncation; lo captures hi's error)
__device__ inline void bf16_split(float x, unsigned short& hi, unsigned short& lo) {
    unsigned int u = __float_as_uint(x);
    hi = (unsigned short)(u >> 16);
    float fh = __uint_as_float(u & 0xffff0000u);
    float l = x - fh;
    lo = (unsigned short)(__float_as_uint(l) >> 16);
}

// ---------------------------------------------------------------------------
// Fused histogram over all three layers' edges
// ---------------------------------------------------------------------------
__global__ void histogram_all(const int* __restrict__ dst0, const int* __restrict__ dst1,
                              const int* __restrict__ dst2, int* __restrict__ cnt) {
    int i = blockIdx.x * blockDim.x + threadIdx.x;
    if (i >= E_ALL) return;
    int k;
    if (i < NE0) {
        k = dst0[i];
    } else if (i < NE0 + NE1) {
        k = RBASE1 + dst1[i - NE0];
    } else {
        k = RBASE2 + dst2[i - NE0 - NE1];
    }
    atomicAdd(&cnt[k], 1);
}

// ---------------------------------------------------------------------------
// Exclusive scan over NROWS counters (chunked: per-1024 scan + totals + add)
// ---------------------------------------------------------------------------
__global__ __launch_bounds__(1024) void scan_block(const int* __restrict__ cnt, int N,
                                                   int* __restrict__ row_start,
                                                   int* __restrict__ blocksum) {
    __shared__ int wsum[16];
    int i = blockIdx.x * 1024 + threadIdx.x;
    int lane = threadIdx.x & 63, wid = threadIdx.x >> 6;
    int v = (i < N) ? cnt[i] : 0;
    int incl = wave_incl_scan(v);
    if (lane == 63) wsum[wid] = incl;
    __syncthreads();
    if (threadIdx.x < 16) {
        int w = wsum[threadIdx.x];
#pragma unroll
        for (int off = 1; off < 16; off <<= 1) {
            int t = __shfl_up(w, off, 64);
            if ((int)threadIdx.x >= off) w += t;
        }
        wsum[threadIdx.x] = w;
    }
    __syncthreads();
    int woff = wid ? wsum[wid - 1] : 0;
    if (i < N) row_start[i] = woff + incl - v;
    if (threadIdx.x == 0) blocksum[blockIdx.x] = wsum[15];
}

__global__ __launch_bounds__(1024) void scan_totals(int* __restrict__ bs, int nb) {
    __shared__ int wsum[16];
    int i = threadIdx.x;
    int lane = i & 63, wid = i >> 6;
    int v = (i < nb) ? bs[i] : 0;
    int incl = wave_incl_scan(v);
    if (lane == 63) wsum[wid] = incl;
    __syncthreads();
    if (i < 16) {
        int w = wsum[i];
#pragma unroll
        for (int off = 1; off < 16; off <<= 1) {
            int t = __shfl_up(w, off, 64);
            if (i >= off) w += t;
        }
        wsum[i] = w;
    }
    __syncthreads();
    int woff = wid ? wsum[wid - 1] : 0;
    if (i < nb) bs[i] = woff + incl - v;
}

__global__ __launch_bounds__(1024) void add_offsets(int* __restrict__ row_start,
                                                    const int* __restrict__ bs, int N, int E,
                                                    int* __restrict__ cursor) {
    int i = blockIdx.x * 1024 + threadIdx.x;
    if (i < N) {
        int s = row_start[i] + bs[blockIdx.x];
        row_start[i] = s;
        cursor[i] = s;
    }
    if (i == 0) row_start[N] = E;
}

// ---------------------------------------------------------------------------
// Fused fill: scatter edge src ids into dst-grouped order (all layers)
// ---------------------------------------------------------------------------
__global__ void fill_all(const int* __restrict__ src0, const int* __restrict__ dst0,
                         const int* __restrict__ src1, const int* __restrict__ dst1,
                         const int* __restrict__ src2, const int* __restrict__ dst2,
                         int* __restrict__ cursor, int* __restrict__ ss) {
    int i = blockIdx.x * blockDim.x + threadIdx.x;
    if (i >= E_ALL) return;
    int k, s;
    if (i < NE0) {
        s = src0[i];
        k = dst0[i];
    } else if (i < NE0 + NE1) {
        int e = i - NE0;
        s = src1[e];
        k = RBASE1 + dst1[e];
    } else {
        int e = i - NE0 - NE1;
        s = src2[e];
        k = RBASE2 + dst2[e];
    }
    int p = atomicAdd(&cursor[k], 1);
    ss[p] = s;
}

// ---------------------------------------------------------------------------
// W1 prep: split + transpose W[256][128] fp32 -> wt_hi/wt_lo [128][256] bf16
// ---------------------------------------------------------------------------
__global__ void wprep(const float* __restrict__ W,
                      unsigned short* __restrict__ Whi, unsigned short* __restrict__ Wlo) {
    int idx = blockIdx.x * 256 + threadIdx.x;          // 32768 = 256*128
    int k = idx >> 7, c = idx & 127;                   // W[k][c]
    unsigned short h, l;
    bf16_split(W[idx], h, l);
    Whi[c * 256 + k] = h;
    Wlo[c * 256 + k] = l;
}

// ---------------------------------------------------------------------------
// Layer-0 gather (F=256): one wave per dst row; writes mean as bf16 hi/lo
// planes (feeds the MFMA GEMM; same total bytes as one fp32 plane).
// Measured ~5.4 TB/s logical = near load-path ceiling.
// ---------------------------------------------------------------------------
__global__ __launch_bounds__(256) void gather256(const float* __restrict__ h,
                                                 const int* __restrict__ rs,
                                                 const int* __restrict__ ss,
                                                 unsigned short* __restrict__ mhi,
                                                 unsigned short* __restrict__ mlo) {
    int lane = threadIdx.x & 63;
    int r = blockIdx.x * 4 + (threadIdx.x >> 6);
    if (r >= NL1) return;
    int s0 = rs[r], s1 = rs[r + 1];
    int tot = s1 - s0;

    const float* hp = h + (size_t)lane * 4;
    float4 acc0 = make_float4(0.f, 0.f, 0.f, 0.f);
    float4 acc1 = make_float4(0.f, 0.f, 0.f, 0.f);
    int e = s0;
    for (; e + 7 < s1; e += 8) {
        int i0 = ss[e], i1 = ss[e + 1], i2 = ss[e + 2], i3 = ss[e + 3];
        int i4 = ss[e + 4], i5 = ss[e + 5], i6 = ss[e + 6], i7 = ss[e + 7];
        float4 v0 = *(const float4*)(hp + (size_t)i0 * F_IN);
        float4 v1 = *(const float4*)(hp + (size_t)i1 * F_IN);
        float4 v2 = *(const float4*)(hp + (size_t)i2 * F_IN);
        float4 v3 = *(const float4*)(hp + (size_t)i3 * F_IN);
        float4 v4 = *(const float4*)(hp + (size_t)i4 * F_IN);
        float4 v5 = *(const float4*)(hp + (size_t)i5 * F_IN);
        float4 v6 = *(const float4*)(hp + (size_t)i6 * F_IN);
        float4 v7 = *(const float4*)(hp + (size_t)i7 * F_IN);
        acc0.x += (v0.x + v1.x) + (v2.x + v3.x);
        acc0.y += (v0.y + v1.y) + (v2.y + v3.y);
        acc0.z += (v0.z + v1.z) + (v2.z + v3.z);
        acc0.w += (v0.w + v1.w) + (v2.w + v3.w);
        acc1.x += (v4.x + v5.x) + (v6.x + v7.x);
        acc1.y += (v4.y + v5.y) + (v6.y + v7.y);
        acc1.z += (v4.z + v5.z) + (v6.z + v7.z);
        acc1.w += (v4.w + v5.w) + (v6.w + v7.w);
    }
    for (; e + 1 < s1; e += 2) {
        int i0 = ss[e], i1 = ss[e + 1];
        float4 v0 = *(const float4*)(hp + (size_t)i0 * F_IN);
        float4 v1 = *(const float4*)(hp + (size_t)i1 * F_IN);
        acc0.x += v0.x + v1.x; acc0.y += v0.y + v1.y;
        acc0.z += v0.z + v1.z; acc0.w += v0.w + v1.w;
    }
    if (e < s1) {
        int i0 = ss[e];
        float4 v0 = *(const float4*)(hp + (size_t)i0 * F_IN);
        acc0.x += v0.x; acc0.y += v0.y; acc0.z += v0.z; acc0.w += v0.w;
    }
    float inv = (tot > 0) ? 1.0f / (float)tot : 0.0f;
    float o[4] = {(acc0.x + acc1.x) * inv, (acc0.y + acc1.y) * inv,
                  (acc0.z + acc1.z) * inv, (acc0.w + acc1.w) * inv};
    ushort4 hv, lv;
    bf16_split(o[0], hv.x, lv.x);
    bf16_split(o[1], hv.y, lv.y);
    bf16_split(o[2], hv.z, lv.z);
    bf16_split(o[3], hv.w, lv.w);
    *(ushort4*)(mhi + (size_t)r * F_IN + lane * 4) = hv;
    *(ushort4*)(mlo + (size_t)r * F_IN + lane * 4) = lv;
}

// ---------------------------------------------------------------------------
// Layer-0 linear via MFMA (Markidis split: hi*hi + hi*lo + lo*hi), W in LDS.
// 1024 thr (16 waves = 4/SIMD), pre-split W staged with vector copies
// (128 KB LDS, XOR-swizzled).  Wave computes one 16x128 strip; grid = N/256.
// A-frag: lane(r+16kg) holds A[row][ks*32+kg*8+j]; B-frag: Wt[ct*16+r][same k]
// C/D: col = lane&15, row = (lane>>4)*4 + reg   [HW-verified mapping]
// ---------------------------------------------------------------------------
__global__ __launch_bounds__(1024) void mfma_lin0(const unsigned short* __restrict__ Ahi,
                                                  const unsigned short* __restrict__ Alo,
                                                  const unsigned short* __restrict__ Whi,
                                                  const unsigned short* __restrict__ Wlo,
                                                  const float* __restrict__ bias,
                                                  float* __restrict__ out, int N) {
    __shared__ unsigned short whi[F_IN * F_HID];   // 64 KB, Wt[c][k] swizzled
    __shared__ unsigned short wlo[F_IN * F_HID];   // 64 KB

    // stage pre-split W (vector copies, swizzled destination)
    for (int ci = threadIdx.x; ci < (F_IN * F_HID) / 8; ci += 1024) {
        int e = ci * 8;                 // element index: c = e>>8, aligned-8 chunk
        int c = e >> 8;
        int swz = e ^ ((c & 7) << 3);
        *(short8v*)(whi + swz) = *(const short8v*)(Whi + e);
        *(short8v*)(wlo + swz) = *(const short8v*)(Wlo + e);
    }
    __syncthreads();

    int lane = threadIdx.x & 63;
    int wid = threadIdx.x >> 6;            // 0..15
    int rowbase = blockIdx.x * 256 + wid * 16;
    int r = lane & 15;
    int kg = lane >> 4;

    size_t arow = (size_t)min(rowbase + r, N - 1);
    const unsigned short* pah = Ahi + arow * F_IN + kg * 8;
    const unsigned short* pal = Alo + arow * F_IN + kg * 8;

    f32x4 acc[8];
#pragma unroll
    for (int ct = 0; ct < 8; ++ct) acc[ct] = (f32x4){0.f, 0.f, 0.f, 0.f};

#pragma unroll
    for (int ks = 0; ks < 8; ++ks) {
        short8v ah = *(const short8v*)(pah + ks * 32);
        short8v al = *(const short8v*)(pal + ks * 32);
#pragma unroll
        for (int ct = 0; ct < 8; ++ct) {
            int e = (((ct * 16 + r) << 8) + ks * 32 + kg * 8) ^ ((r & 7) << 3);
            short8v bh = *(const short8v*)(whi + e);
            short8v bl = *(const short8v*)(wlo + e);
            acc[ct] = __builtin_amdgcn_mfma_f32_16x16x32_bf16(ah, bh, acc[ct], 0, 0, 0);
            acc[ct] = __builtin_amdgcn_mfma_f32_16x16x32_bf16(ah, bl, acc[ct], 0, 0, 0);
            acc[ct] = __builtin_amdgcn_mfma_f32_16x16x32_bf16(al, bh, acc[ct], 0, 0, 0);
        }
    }

    // epilogue: bias + relu
    int crow = rowbase + kg * 4;
#pragma unroll
    for (int ct = 0; ct < 8; ++ct) {
        float bb = bias[ct * 16 + r];
#pragma unroll
        for (int i = 0; i < 4; ++i) {
            int rr = crow + i;
            if (rr < N) out[(size_t)rr * F_HID + ct * 16 + r] = fmaxf(acc[ct][i] + bb, 0.f);
        }
    }
}

// ---------------------------------------------------------------------------
// Fused gather + mean + linear for F_HID-wide layers (layers 1 and 2).
// Gather phase: 2 edges per wave (half-wave h handles edge e+h with
// float4/lane = full 512B row), halves combined via shfl(lane^32).
// ---------------------------------------------------------------------------
template <int FOUT, int ROWS, bool RELU>
__global__ __launch_bounds__(256) void gather_linear(const float* __restrict__ h,
                                                     const int* __restrict__ rs,
                                                     const int* __restrict__ ss,
                                                     const float* __restrict__ W,
                                                     const float* __restrict__ bias,
                                                     float* __restrict__ out,
                                                     int N, int rowbase) {
    __shared__ float wtile[128 * FOUT];
    __shared__ float mr[ROWS][128];

    if constexpr (FOUT % 4 == 0) {
        for (int idx = threadIdx.x * 4; idx < 128 * FOUT; idx += 1024)
            *(float4*)&wtile[idx] = *(const float4*)&W[idx];
    } else {
        for (int idx = threadIdx.x; idx < 128 * FOUT; idx += 256)
            wtile[idx] = W[idx];
    }

    int lane = threadIdx.x & 63;
    int w = threadIdx.x >> 6;
    int half = lane >> 5;          // 0 or 1: which edge of the pair
    int hl = lane & 31;            // 32 lanes x float4 = 128 floats = full row
    int rb = blockIdx.x * ROWS;
    constexpr int RPW = ROWS / 4;
#pragma unroll
    for (int q = 0; q < RPW; ++q) {
        int lr = w * RPW + q;
        int r = rb + lr;
        float4 acc = make_float4(0.f, 0.f, 0.f, 0.f);
        if (r < N) {
            int s0 = rs[rowbase + r], s1 = rs[rowbase + r + 1];
            const float* hp = h + (size_t)hl * 4;
            int e = s0;
            for (; e + 3 < s1; e += 4) {
                int i0 = ss[e + half], i1 = ss[e + 2 + half];
                float4 v0 = *(const float4*)(hp + (size_t)i0 * F_HID);
                float4 v1 = *(const float4*)(hp + (size_t)i1 * F_HID);
                acc.x += v0.x + v1.x; acc.y += v0.y + v1.y;
                acc.z += v0.z + v1.z; acc.w += v0.w + v1.w;
            }
            if (e + 1 < s1) {
                int i0 = ss[e + half];
                float4 v0 = *(const float4*)(hp + (size_t)i0 * F_HID);
                acc.x += v0.x; acc.y += v0.y; acc.z += v0.z; acc.w += v0.w;
                e += 2;
            }
            if (e < s1 && half == 0) {
                int i0 = ss[e];
                float4 v0 = *(const float4*)(hp + (size_t)i0 * F_HID);
                acc.x += v0.x; acc.y += v0.y; acc.z += v0.z; acc.w += v0.w;
            }
            // combine the two half-wave accumulators
            acc.x += __shfl(acc.x, lane ^ 32);
            acc.y += __shfl(acc.y, lane ^ 32);
            acc.z += __shfl(acc.z, lane ^ 32);
            acc.w += __shfl(acc.w, lane ^ 32);
            float inv = (s1 > s0) ? 1.0f / (float)(s1 - s0) : 0.0f;
            acc.x *= inv; acc.y *= inv; acc.z *= inv; acc.w *= inv;
        }
        if (half == 0) *(float4*)&mr[lr][hl * 4] = acc;
    }
    __syncthreads();

    if constexpr (FOUT == 128) {
        int c4 = (threadIdx.x & 31) * 4;
        int r0 = (threadIdx.x >> 5) & 7;
        float4 bb = *(const float4*)&bias[c4];
        float4 a0 = bb, a1 = bb;
#pragma unroll 8
        for (int k = 0; k < 128; ++k) {
            float4 wv = *(const float4*)&wtile[k * 128 + c4];
            float m0 = mr[r0][k];
            float m1 = mr[r0 + 8][k];
            a0.x += m0 * wv.x; a0.y += m0 * wv.y; a0.z += m0 * wv.z; a0.w += m0 * wv.w;
            a1.x += m1 * wv.x; a1.y += m1 * wv.y; a1.z += m1 * wv.z; a1.w += m1 * wv.w;
        }
        if (RELU) {
            a0.x = fmaxf(a0.x, 0.f); a0.y = fmaxf(a0.y, 0.f);
            a0.z = fmaxf(a0.z, 0.f); a0.w = fmaxf(a0.w, 0.f);
            a1.x = fmaxf(a1.x, 0.f); a1.y = fmaxf(a1.y, 0.f);
            a1.z = fmaxf(a1.z, 0.f); a1.w = fmaxf(a1.w, 0.f);
        }
        int ra = rb + r0, rb2 = rb + r0 + 8;
        if (ra < N) *(float4*)&out[(size_t)ra * 128 + c4] = a0;
        if (rb2 < N) *(float4*)&out[(size_t)rb2 * 128 + c4] = a1;
    } else {
        int j = lane;
        int rg = w;
        if (j < FOUT) {
            float bb = bias[j];
            float a0 = bb, a1 = bb;
#pragma unroll 8
            for (int k = 0; k < 128; ++k) {
                float wv = wtile[k * FOUT + j];
                a0 += mr[rg][k] * wv;
                a1 += mr[rg + 4][k] * wv;
            }
            if (RELU) { a0 = fmaxf(a0, 0.f); a1 = fmaxf(a1, 0.f); }
            int ra = rb + rg, rb2 = rb + rg + 4;
            if (ra < N) out[(size_t)ra * FOUT + j] = a0;
            if (rb2 < N) out[(size_t)rb2 * FOUT + j] = a1;
        }
    }
}

// ---------------------------------------------------------------------------

static inline size_t align256(size_t x) { return (x + 255) & ~size_t(255); }

extern "C" void kernel_launch(void* const* d_in, const int* in_sizes, int n_in,
                              void* d_out, int out_size, void* d_ws, size_t ws_size,
                              hipStream_t stream) {
    const float* features = (const float*)d_in[0];
    const int*   src0     = (const int*)d_in[1];
    const int*   dst0     = (const int*)d_in[2];
    const int*   src1     = (const int*)d_in[3];
    const int*   dst1     = (const int*)d_in[4];
    const int*   src2     = (const int*)d_in[5];
    const int*   dst2     = (const int*)d_in[6];
    const float* W1       = (const float*)d_in[7];
    const float* b1       = (const float*)d_in[8];
    const float* W2       = (const float*)d_in[9];
    const float* b2       = (const float*)d_in[10];
    const float* W3       = (const float*)d_in[11];
    const float* b3       = (const float*)d_in[12];
    float* out = (float*)d_out;

    char* p = (char*)d_ws;
    size_t off = 0;
    auto alloc = [&](size_t bytes) {
        char* r = p + off;
        off += align256(bytes);
        return r;
    };
    unsigned short* m0hi = (unsigned short*)alloc(sizeof(unsigned short) * (size_t)NL1 * F_IN);
    unsigned short* m0lo = (unsigned short*)alloc(sizeof(unsigned short) * (size_t)NL1 * F_IN);
    unsigned short* wt_hi = (unsigned short*)alloc(sizeof(unsigned short) * F_IN * F_HID);
    unsigned short* wt_lo = (unsigned short*)alloc(sizeof(unsigned short) * F_IN * F_HID);
    float* h1 = (float*)alloc(sizeof(float) * (size_t)NL1 * F_HID);
    float* h2 = (float*)alloc(sizeof(float) * (size_t)NL2 * F_HID);
    int* cnt = (int*)alloc(sizeof(int) * NROWS);
    int* rs  = (int*)alloc(sizeof(int) * (NROWS + 1));
    int* cur = (int*)alloc(sizeof(int) * NROWS);
    int* bs  = (int*)alloc(sizeof(int) * 1024);
    int* ss  = (int*)alloc(sizeof(int) * E_ALL);
    (void)ws_size;

    // ---- Fused CSR build over all layers (hierarchical scan, all tiny) ----
    hipMemsetAsync(cnt, 0, sizeof(int) * NROWS, stream);
    histogram_all<<<(E_ALL + 255) / 256, 256, 0, stream>>>(dst0, dst1, dst2, cnt);
    int nb = (NROWS + 1023) / 1024;
    scan_block<<<nb, 1024, 0, stream>>>(cnt, NROWS, rs, bs);
    scan_totals<<<1, 1024, 0, stream>>>(bs, nb);
    add_offsets<<<nb, 1024, 0, stream>>>(rs, bs, NROWS, E_ALL, cur);
    fill_all<<<(E_ALL + 255) / 256, 256, 0, stream>>>(src0, dst0, src1, dst1, src2, dst2,
                                                      cur, ss);

    // ---- W1 split+transpose prep (tiny) ----
    wprep<<<(F_IN * F_HID) / 256, 256, 0, stream>>>(W1, wt_hi, wt_lo);

    // ---- Layer 0 -> 1: gather (bf16 hi/lo out) + MFMA split-GEMM (W in LDS) ----
    gather256<<<NL1 / 4, 256, 0, stream>>>(features, rs, ss, m0hi, m0lo);
    mfma_lin0<<<(NL1 + 255) / 256, 1024, 0, stream>>>(m0hi, m0lo, wt_hi, wt_lo, b1, h1, NL1);

    // ---- Layer 1 -> 2 (fused gather+mean+linear) ----
    gather_linear<128, 16, true><<<(NL2 + 15) / 16, 256, 0, stream>>>(
        h1, rs, ss, W2, b2, h2, NL2, RBASE1);

    // ---- Layer 2 -> 3 (fused gather+mean+linear, no relu) ----
    gather_linear<F_OUT, 8, false><<<(NL3 + 7) / 8, 256, 0, stream>>>(
        h2, rs, ss, W3, b3, out, NL3, RBASE2);
}

// Round 12
// 372.744 us; speedup vs baseline: 1.1755x; 1.0944x over previous
//
#include <hip/hip_runtime.h>

// Problem constants (from reference)
#define NL0 300000
#define NL1 60000
#define NL2 15000
#define NL3 4000
#define NE0 960000
#define NE1 240000
#define NE2 64000
#define E_ALL (NE0 + NE1 + NE2)
#define F_IN 256
#define F_HID 128
#define F_OUT 47

// Concatenated CSR row layout:
//   [0, 60000)        : layer0 dst
//   [60000, 75000)    : layer1 dst
//   [75000, 79000)    : layer2 dst
#define RBASE1 NL1
#define RBASE2 (NL1 + NL2)
#define NROWS (NL1 + NL2 + NL3)

#define FILL_BLOCKS ((E_ALL + 255) / 256)
#define WPREP_BLOCKS ((F_IN * F_HID) / 256)

typedef __attribute__((ext_vector_type(8))) short short8v;   // 8 bf16 (4 VGPR)
typedef __attribute__((ext_vector_type(4))) float f32x4;

// ---------------------------------------------------------------------------
// Wave-wide (64-lane) inclusive scan
// ---------------------------------------------------------------------------
__device__ inline int wave_incl_scan(int v) {
    int lane = threadIdx.x & 63;
#pragma unroll
    for (int off = 1; off < 64; off <<= 1) {
        int t = __shfl_up(v, off, 64);
        if (lane >= off) v += t;
    }
    return v;
}

// fp32 -> (bf16 hi, bf16 lo) split (truncation; lo captures hi's error)
__device__ inline void bf16_split(float x, unsigned short& hi, unsigned short& lo) {
    unsigned int u = __float_as_uint(x);
    hi = (unsigned short)(u >> 16);
    float fh = __uint_as_float(u & 0xffff0000u);
    float l = x - fh;
    lo = (unsigned short)(__float_as_uint(l) >> 16);
}

// ---------------------------------------------------------------------------
// Fused histogram over all three layers' edges
// ---------------------------------------------------------------------------
__global__ void histogram_all(const int* __restrict__ dst0, const int* __restrict__ dst1,
                              const int* __restrict__ dst2, int* __restrict__ cnt) {
    int i = blockIdx.x * blockDim.x + threadIdx.x;
    if (i >= E_ALL) return;
    int k;
    if (i < NE0) {
        k = dst0[i];
    } else if (i < NE0 + NE1) {
        k = RBASE1 + dst1[i - NE0];
    } else {
        k = RBASE2 + dst2[i - NE0 - NE1];
    }
    atomicAdd(&cnt[k], 1);
}

// ---------------------------------------------------------------------------
// Exclusive scan step 1: per-1024-chunk scan (chunk-local excl -> rs,
// chunk totals -> bs)
// ---------------------------------------------------------------------------
__global__ __launch_bounds__(1024) void scan_block(const int* __restrict__ cnt, int N,
                                                   int* __restrict__ row_start,
                                                   int* __restrict__ blocksum) {
    __shared__ int wsum[16];
    int i = blockIdx.x * 1024 + threadIdx.x;
    int lane = threadIdx.x & 63, wid = threadIdx.x >> 6;
    int v = (i < N) ? cnt[i] : 0;
    int incl = wave_incl_scan(v);
    if (lane == 63) wsum[wid] = incl;
    __syncthreads();
    if (threadIdx.x < 16) {
        int w = wsum[threadIdx.x];
#pragma unroll
        for (int off = 1; off < 16; off <<= 1) {
            int t = __shfl_up(w, off, 64);
            if ((int)threadIdx.x >= off) w += t;
        }
        wsum[threadIdx.x] = w;
    }
    __syncthreads();
    int woff = wid ? wsum[wid - 1] : 0;
    if (i < N) row_start[i] = woff + incl - v;
    if (threadIdx.x == 0) blocksum[blockIdx.x] = wsum[15];
}

// ---------------------------------------------------------------------------
// Exclusive scan step 2 (fused): each block computes its own prefix over the
// raw chunk totals bs[0..blockIdx.x) with one wave, then adds it.
// ---------------------------------------------------------------------------
__global__ __launch_bounds__(1024) void add_offsets2(int* __restrict__ row_start,
                                                     const int* __restrict__ bs, int N, int E,
                                                     int* __restrict__ cursor) {
    __shared__ int soff;
    if (threadIdx.x < 64) {
        int s = 0;
        for (int j = threadIdx.x; j < blockIdx.x; j += 64) s += bs[j];
#pragma unroll
        for (int o = 32; o >= 1; o >>= 1) s += __shfl_xor(s, o, 64);
        if (threadIdx.x == 0) soff = s;
    }
    __syncthreads();
    int i = blockIdx.x * 1024 + threadIdx.x;
    if (i < N) {
        int v = row_start[i] + soff;
        row_start[i] = v;
        cursor[i] = v;
    }
    if (i == 0) row_start[N] = E;
}

// ---------------------------------------------------------------------------
// Fused fill (+ trailing wprep blocks): scatter edge src ids into dst-grouped
// order; last WPREP_BLOCKS blocks split+transpose W1 -> wt_hi/wt_lo.
// ---------------------------------------------------------------------------
__global__ void fill_all(const int* __restrict__ src0, const int* __restrict__ dst0,
                         const int* __restrict__ src1, const int* __restrict__ dst1,
                         const int* __restrict__ src2, const int* __restrict__ dst2,
                         int* __restrict__ cursor, int* __restrict__ ss,
                         const float* __restrict__ W1,
                         unsigned short* __restrict__ Whi,
                         unsigned short* __restrict__ Wlo) {
    int b = blockIdx.x;
    if (b >= FILL_BLOCKS) {
        int idx = (b - FILL_BLOCKS) * 256 + threadIdx.x;   // 32768 = 256*128
        int k = idx >> 7, c = idx & 127;                   // W1[k][c]
        unsigned short h, l;
        bf16_split(W1[idx], h, l);
        Whi[c * 256 + k] = h;
        Wlo[c * 256 + k] = l;
        return;
    }
    int i = b * 256 + threadIdx.x;
    if (i >= E_ALL) return;
    int k, s;
    if (i < NE0) {
        s = src0[i];
        k = dst0[i];
    } else if (i < NE0 + NE1) {
        int e = i - NE0;
        s = src1[e];
        k = RBASE1 + dst1[e];
    } else {
        int e = i - NE0 - NE1;
        s = src2[e];
        k = RBASE2 + dst2[e];
    }
    int p = atomicAdd(&cursor[k], 1);
    ss[p] = s;
}

// ---------------------------------------------------------------------------
// Layer-0 gather (F=256): one wave per dst row; writes mean as bf16 hi/lo
// planes.  Measured ~5.4 TB/s logical = near load-path ceiling.
// ---------------------------------------------------------------------------
__global__ __launch_bounds__(256) void gather256(const float* __restrict__ h,
                                                 const int* __restrict__ rs,
                                                 const int* __restrict__ ss,
                                                 unsigned short* __restrict__ mhi,
                                                 unsigned short* __restrict__ mlo) {
    int lane = threadIdx.x & 63;
    int r = blockIdx.x * 4 + (threadIdx.x >> 6);
    if (r >= NL1) return;
    int s0 = rs[r], s1 = rs[r + 1];
    int tot = s1 - s0;

    const float* hp = h + (size_t)lane * 4;
    float4 acc0 = make_float4(0.f, 0.f, 0.f, 0.f);
    float4 acc1 = make_float4(0.f, 0.f, 0.f, 0.f);
    int e = s0;
    for (; e + 7 < s1; e += 8) {
        int i0 = ss[e], i1 = ss[e + 1], i2 = ss[e + 2], i3 = ss[e + 3];
        int i4 = ss[e + 4], i5 = ss[e + 5], i6 = ss[e + 6], i7 = ss[e + 7];
        float4 v0 = *(const float4*)(hp + (size_t)i0 * F_IN);
        float4 v1 = *(const float4*)(hp + (size_t)i1 * F_IN);
        float4 v2 = *(const float4*)(hp + (size_t)i2 * F_IN);
        float4 v3 = *(const float4*)(hp + (size_t)i3 * F_IN);
        float4 v4 = *(const float4*)(hp + (size_t)i4 * F_IN);
        float4 v5 = *(const float4*)(hp + (size_t)i5 * F_IN);
        float4 v6 = *(const float4*)(hp + (size_t)i6 * F_IN);
        float4 v7 = *(const float4*)(hp + (size_t)i7 * F_IN);
        acc0.x += (v0.x + v1.x) + (v2.x + v3.x);
        acc0.y += (v0.y + v1.y) + (v2.y + v3.y);
        acc0.z += (v0.z + v1.z) + (v2.z + v3.z);
        acc0.w += (v0.w + v1.w) + (v2.w + v3.w);
        acc1.x += (v4.x + v5.x) + (v6.x + v7.x);
        acc1.y += (v4.y + v5.y) + (v6.y + v7.y);
        acc1.z += (v4.z + v5.z) + (v6.z + v7.z);
        acc1.w += (v4.w + v5.w) + (v6.w + v7.w);
    }
    for (; e + 1 < s1; e += 2) {
        int i0 = ss[e], i1 = ss[e + 1];
        float4 v0 = *(const float4*)(hp + (size_t)i0 * F_IN);
        float4 v1 = *(const float4*)(hp + (size_t)i1 * F_IN);
        acc0.x += v0.x + v1.x; acc0.y += v0.y + v1.y;
        acc0.z += v0.z + v1.z; acc0.w += v0.w + v1.w;
    }
    if (e < s1) {
        int i0 = ss[e];
        float4 v0 = *(const float4*)(hp + (size_t)i0 * F_IN);
        acc0.x += v0.x; acc0.y += v0.y; acc0.z += v0.z; acc0.w += v0.w;
    }
    float inv = (tot > 0) ? 1.0f / (float)tot : 0.0f;
    float o[4] = {(acc0.x + acc1.x) * inv, (acc0.y + acc1.y) * inv,
                  (acc0.z + acc1.z) * inv, (acc0.w + acc1.w) * inv};
    ushort4 hv, lv;
    bf16_split(o[0], hv.x, lv.x);
    bf16_split(o[1], hv.y, lv.y);
    bf16_split(o[2], hv.z, lv.z);
    bf16_split(o[3], hv.w, lv.w);
    *(ushort4*)(mhi + (size_t)r * F_IN + lane * 4) = hv;
    *(ushort4*)(mlo + (size_t)r * F_IN + lane * 4) = lv;
}

// ---------------------------------------------------------------------------
// Layer-0 linear via MFMA (Markidis split: hi*hi + hi*lo + lo*hi), W in LDS.
// 1024 thr (16 waves = 4/SIMD), pre-split W staged with vector copies
// (128 KB LDS, XOR-swizzled).  Wave computes one 16x128 strip; grid = N/256.
// C/D: col = lane&15, row = (lane>>4)*4 + reg   [HW-verified mapping]
// ---------------------------------------------------------------------------
__global__ __launch_bounds__(1024) void mfma_lin0(const unsigned short* __restrict__ Ahi,
                                                  const unsigned short* __restrict__ Alo,
                                                  const unsigned short* __restrict__ Whi,
                                                  const unsigned short* __restrict__ Wlo,
                                                  const float* __restrict__ bias,
                                                  float* __restrict__ out, int N) {
    __shared__ unsigned short whi[F_IN * F_HID];   // 64 KB, Wt[c][k] swizzled
    __shared__ unsigned short wlo[F_IN * F_HID];   // 64 KB

    for (int ci = threadIdx.x; ci < (F_IN * F_HID) / 8; ci += 1024) {
        int e = ci * 8;
        int c = e >> 8;
        int swz = e ^ ((c & 7) << 3);
        *(short8v*)(whi + swz) = *(const short8v*)(Whi + e);
        *(short8v*)(wlo + swz) = *(const short8v*)(Wlo + e);
    }
    __syncthreads();

    int lane = threadIdx.x & 63;
    int wid = threadIdx.x >> 6;            // 0..15
    int rowbase = blockIdx.x * 256 + wid * 16;
    int r = lane & 15;
    int kg = lane >> 4;

    size_t arow = (size_t)min(rowbase + r, N - 1);
    const unsigned short* pah = Ahi + arow * F_IN + kg * 8;
    const unsigned short* pal = Alo + arow * F_IN + kg * 8;

    f32x4 acc[8];
#pragma unroll
    for (int ct = 0; ct < 8; ++ct) acc[ct] = (f32x4){0.f, 0.f, 0.f, 0.f};

#pragma unroll
    for (int ks = 0; ks < 8; ++ks) {
        short8v ah = *(const short8v*)(pah + ks * 32);
        short8v al = *(const short8v*)(pal + ks * 32);
#pragma unroll
        for (int ct = 0; ct < 8; ++ct) {
            int e = (((ct * 16 + r) << 8) + ks * 32 + kg * 8) ^ ((r & 7) << 3);
            short8v bh = *(const short8v*)(whi + e);
            short8v bl = *(const short8v*)(wlo + e);
            acc[ct] = __builtin_amdgcn_mfma_f32_16x16x32_bf16(ah, bh, acc[ct], 0, 0, 0);
            acc[ct] = __builtin_amdgcn_mfma_f32_16x16x32_bf16(ah, bl, acc[ct], 0, 0, 0);
            acc[ct] = __builtin_amdgcn_mfma_f32_16x16x32_bf16(al, bh, acc[ct], 0, 0, 0);
        }
    }

    int crow = rowbase + kg * 4;
#pragma unroll
    for (int ct = 0; ct < 8; ++ct) {
        float bb = bias[ct * 16 + r];
#pragma unroll
        for (int i = 0; i < 4; ++i) {
            int rr = crow + i;
            if (rr < N) out[(size_t)rr * F_HID + ct * 16 + r] = fmaxf(acc[ct][i] + bb, 0.f);
        }
    }
}

// ---------------------------------------------------------------------------
// Fused gather + mean + linear for F_HID-wide layers (layers 1 and 2).
// Gather: 2 edges per wave (half-wave h reads edge e+h, float4/lane = full
// 512B row), combined via shfl(lane^32).  GEMM reads W straight from global
// (L1/L2-resident; no wtile) -> LDS = mr only (8 KB) -> 8 blocks/CU.
// ---------------------------------------------------------------------------
template <int FOUT, int ROWS, bool RELU>
__global__ __launch_bounds__(256) void gather_linear(const float* __restrict__ h,
                                                     const int* __restrict__ rs,
                                                     const int* __restrict__ ss,
                                                     const float* __restrict__ W,
                                                     const float* __restrict__ bias,
                                                     float* __restrict__ out,
                                                     int N, int rowbase) {
    __shared__ float mr[ROWS][128];

    int lane = threadIdx.x & 63;
    int w = threadIdx.x >> 6;
    int half = lane >> 5;          // 0 or 1: which edge of the pair
    int hl = lane & 31;            // 32 lanes x float4 = 128 floats = full row
    int rb = blockIdx.x * ROWS;
    constexpr int RPW = ROWS / 4;
#pragma unroll
    for (int q = 0; q < RPW; ++q) {
        int lr = w * RPW + q;
        int r = rb + lr;
        float4 acc = make_float4(0.f, 0.f, 0.f, 0.f);
        if (r < N) {
            int s0 = rs[rowbase + r], s1 = rs[rowbase + r + 1];
            const float* hp = h + (size_t)hl * 4;
            int e = s0;
            for (; e + 3 < s1; e += 4) {
                int i0 = ss[e + half], i1 = ss[e + 2 + half];
                float4 v0 = *(const float4*)(hp + (size_t)i0 * F_HID);
                float4 v1 = *(const float4*)(hp + (size_t)i1 * F_HID);
                acc.x += v0.x + v1.x; acc.y += v0.y + v1.y;
                acc.z += v0.z + v1.z; acc.w += v0.w + v1.w;
            }
            if (e + 1 < s1) {
                int i0 = ss[e + half];
                float4 v0 = *(const float4*)(hp + (size_t)i0 * F_HID);
                acc.x += v0.x; acc.y += v0.y; acc.z += v0.z; acc.w += v0.w;
                e += 2;
            }
            if (e < s1 && half == 0) {
                int i0 = ss[e];
                float4 v0 = *(const float4*)(hp + (size_t)i0 * F_HID);
                acc.x += v0.x; acc.y += v0.y; acc.z += v0.z; acc.w += v0.w;
            }
            acc.x += __shfl(acc.x, lane ^ 32);
            acc.y += __shfl(acc.y, lane ^ 32);
            acc.z += __shfl(acc.z, lane ^ 32);
            acc.w += __shfl(acc.w, lane ^ 32);
            float inv = (s1 > s0) ? 1.0f / (float)(s1 - s0) : 0.0f;
            acc.x *= inv; acc.y *= inv; acc.z *= inv; acc.w *= inv;
        }
        if (half == 0) *(float4*)&mr[lr][hl * 4] = acc;
    }
    __syncthreads();

    if constexpr (FOUT == 128) {
        int c4 = (threadIdx.x & 31) * 4;
        int r0 = (threadIdx.x >> 5) & 7;
        float4 bb = *(const float4*)&bias[c4];
        float4 a0 = bb, a1 = bb;
#pragma unroll 8
        for (int k = 0; k < 128; ++k) {
            float4 wv = *(const float4*)&W[k * 128 + c4];
            float m0 = mr[r0][k];
            float m1 = mr[r0 + 8][k];
            a0.x += m0 * wv.x; a0.y += m0 * wv.y; a0.z += m0 * wv.z; a0.w += m0 * wv.w;
            a1.x += m1 * wv.x; a1.y += m1 * wv.y; a1.z += m1 * wv.z; a1.w += m1 * wv.w;
        }
        if (RELU) {
            a0.x = fmaxf(a0.x, 0.f); a0.y = fmaxf(a0.y, 0.f);
            a0.z = fmaxf(a0.z, 0.f); a0.w = fmaxf(a0.w, 0.f);
            a1.x = fmaxf(a1.x, 0.f); a1.y = fmaxf(a1.y, 0.f);
            a1.z = fmaxf(a1.z, 0.f); a1.w = fmaxf(a1.w, 0.f);
        }
        int ra = rb + r0, rb2 = rb + r0 + 8;
        if (ra < N) *(float4*)&out[(size_t)ra * 128 + c4] = a0;
        if (rb2 < N) *(float4*)&out[(size_t)rb2 * 128 + c4] = a1;
    } else {
        int j = lane;
        int rg = w;
        if (j < FOUT) {
            float bb = bias[j];
            float a0 = bb, a1 = bb;
#pragma unroll 8
            for (int k = 0; k < 128; ++k) {
                float wv = W[k * FOUT + j];
                a0 += mr[rg][k] * wv;
                a1 += mr[rg + 4][k] * wv;
            }
            if (RELU) { a0 = fmaxf(a0, 0.f); a1 = fmaxf(a1, 0.f); }
            int ra = rb + rg, rb2 = rb + rg + 4;
            if (ra < N) out[(size_t)ra * FOUT + j] = a0;
            if (rb2 < N) out[(size_t)rb2 * FOUT + j] = a1;
        }
    }
}

// ---------------------------------------------------------------------------

static inline size_t align256(size_t x) { return (x + 255) & ~size_t(255); }

extern "C" void kernel_launch(void* const* d_in, const int* in_sizes, int n_in,
                              void* d_out, int out_size, void* d_ws, size_t ws_size,
                              hipStream_t stream) {
    const float* features = (const float*)d_in[0];
    const int*   src0     = (const int*)d_in[1];
    const int*   dst0     = (const int*)d_in[2];
    const int*   src1     = (const int*)d_in[3];
    const int*   dst1     = (const int*)d_in[4];
    const int*   src2     = (const int*)d_in[5];
    const int*   dst2     = (const int*)d_in[6];
    const float* W1       = (const float*)d_in[7];
    const float* b1       = (const float*)d_in[8];
    const float* W2       = (const float*)d_in[9];
    const float* b2       = (const float*)d_in[10];
    const float* W3       = (const float*)d_in[11];
    const float* b3       = (const float*)d_in[12];
    float* out = (float*)d_out;

    char* p = (char*)d_ws;
    size_t off = 0;
    auto alloc = [&](size_t bytes) {
        char* r = p + off;
        off += align256(bytes);
        return r;
    };
    unsigned short* m0hi = (unsigned short*)alloc(sizeof(unsigned short) * (size_t)NL1 * F_IN);
    unsigned short* m0lo = (unsigned short*)alloc(sizeof(unsigned short) * (size_t)NL1 * F_IN);
    unsigned short* wt_hi = (unsigned short*)alloc(sizeof(unsigned short) * F_IN * F_HID);
    unsigned short* wt_lo = (unsigned short*)alloc(sizeof(unsigned short) * F_IN * F_HID);
    float* h1 = (float*)alloc(sizeof(float) * (size_t)NL1 * F_HID);
    float* h2 = (float*)alloc(sizeof(float) * (size_t)NL2 * F_HID);
    int* cnt = (int*)alloc(sizeof(int) * NROWS);
    int* rs  = (int*)alloc(sizeof(int) * (NROWS + 1));
    int* cur = (int*)alloc(sizeof(int) * NROWS);
    int* bs  = (int*)alloc(sizeof(int) * 1024);
    int* ss  = (int*)alloc(sizeof(int) * E_ALL);
    (void)ws_size;

    // ---- Fused CSR build (memset + histogram + 2-kernel scan + fill/wprep) ----
    hipMemsetAsync(cnt, 0, sizeof(int) * NROWS, stream);
    histogram_all<<<(E_ALL + 255) / 256, 256, 0, stream>>>(dst0, dst1, dst2, cnt);
    int nb = (NROWS + 1023) / 1024;
    scan_block<<<nb, 1024, 0, stream>>>(cnt, NROWS, rs, bs);
    add_offsets2<<<nb, 1024, 0, stream>>>(rs, bs, NROWS, E_ALL, cur);
    fill_all<<<FILL_BLOCKS + WPREP_BLOCKS, 256, 0, stream>>>(
        src0, dst0, src1, dst1, src2, dst2, cur, ss, W1, wt_hi, wt_lo);

    // ---- Layer 0 -> 1: gather (bf16 hi/lo out) + MFMA split-GEMM (W in LDS) ----
    gather256<<<NL1 / 4, 256, 0, stream>>>(features, rs, ss, m0hi, m0lo);
    mfma_lin0<<<(NL1 + 255) / 256, 1024, 0, stream>>>(m0hi, m0lo, wt_hi, wt_lo, b1, h1, NL1);

    // ---- Layer 1 -> 2 (fused gather+mean+linear, no W staging) ----
    gather_linear<128, 16, true><<<(NL2 + 15) / 16, 256, 0, stream>>>(
        h1, rs, ss, W2, b2, h2, NL2, RBASE1);

    // ---- Layer 2 -> 3 (fused gather+mean+linear, no relu) ----
    gather_linear<F_OUT, 8, false><<<(NL3 + 7) / 8, 256, 0, stream>>>(
        h2, rs, ss, W3, b3, out, NL3, RBASE2);
}